// Round 6
// baseline (596.490 us; speedup 1.0000x reference)
//
#include <hip/hip_runtime.h>

typedef unsigned short u16;
typedef unsigned int u32;
typedef __bf16 bf16x8 __attribute__((ext_vector_type(8)));
typedef float f32x4 __attribute__((ext_vector_type(4)));

__device__ __forceinline__ u16 f2bf(float f) {
  u32 u = __float_as_uint(f);
  u += 0x7fffu + ((u >> 16) & 1u);
  return (u16)(u >> 16);
}
__device__ __forceinline__ float bf2f(u16 h) {
  return __uint_as_float(((u32)h) << 16);
}

#define GLD_LDS16(g, l)                                                        \
  __builtin_amdgcn_global_load_lds(                                            \
      (__attribute__((address_space(1))) void*)(g),                            \
      (__attribute__((address_space(3))) void*)(l), 16, 0, 0)

// ---------------- init: zero stat/pool buffers + all three halos ------------
// grid = 83: [0,35) smallb, [35,51) in1 halo, [51,67) in2, [67,83) in3.
__global__ __launch_bounds__(256) void init_k(float* smallb, u16* in1, u16* in2,
                                              u16* in3) {
  int bid = blockIdx.x;
  if (bid < 35) {
    int i = bid * 256 + threadIdx.x;
    if (i < 8708) smallb[i] = 0.f;
    return;
  }
  u16* buf;
  int C, sub;
  if (bid < 51)      { buf = in1; C = 576; sub = bid - 35; }
  else if (bid < 67) { buf = in2; C = 256; sub = bid - 51; }
  else               { buf = in3; C = 128; sub = bid - 67; }
  int b = sub >> 2, s = sub & 3;
  int npx = (s < 2) ? 130 : 128;
  u32* base = (u32*)(buf + (size_t)b * 130 * 130 * C);
  int C2 = C >> 1;
  int total = npx * C2;
  for (int i = threadIdx.x; i < total; i += 256) {
    int p = i / C2, r = i - p * C2;
    int y, x;
    if (s == 0)      { y = 0;     x = p; }
    else if (s == 1) { y = 129;   x = p; }
    else if (s == 2) { y = p + 1; x = 0; }
    else             { y = p + 1; x = 129; }
    base[(y * 130 + x) * C2 + r] = 0u;
  }
}

// ------- weight repack: OIHW fp32 -> [CIN/32][9][COUT][32] bf16, all 3 ------
__global__ __launch_bounds__(256) void repack_all(const float* __restrict__ w1,
                                                  u16* __restrict__ wp1,
                                                  const float* __restrict__ w2,
                                                  u16* __restrict__ wp2,
                                                  const float* __restrict__ w3,
                                                  u16* __restrict__ wp3) {
  int bid = blockIdx.x;
  const float* src;
  u16* dst;
  int CIN, COUT, total, base;
  if (bid < 5184)      { src = w1; dst = wp1; CIN = 576; COUT = 256; total = 1327104; base = bid; }
  else if (bid < 6336) { src = w2; dst = wp2; CIN = 256; COUT = 128; total = 294912;  base = bid - 5184; }
  else                 { src = w3; dst = wp3; CIN = 128; COUT = 64;  total = 73728;   base = bid - 6336; }
  int idx = base * 256 + threadIdx.x;
  if (idx >= total) return;
  int kc = idx & 31;
  int n = (idx >> 5) % COUT;
  int q = idx / (32 * COUT);
  int dydx = q % 9, cb = q / 9;
  dst[idx] = f2bf(src[((size_t)n * CIN + cb * 32 + kc) * 9 + dydx]);
}

// ---- x NCHW fp32 -> in1 interior NHWC bf16 (ch 0..511) + coord feats -------
__global__ __launch_bounds__(256) void transpose_x(const float* __restrict__ x,
                                                   const float* __restrict__ wcd,
                                                   const float* __restrict__ bcd,
                                                   u16* __restrict__ in1) {
  const int bid = blockIdx.x;
  const int b = bid >> 8, h = (bid >> 1) & 127, half = bid & 1;
  const int w0 = half * 64;
  const int t = threadIdx.x;
  __shared__ u16 tile[128 * 65];
  __shared__ float swc[128], sbc[64];
  if (t < 128) swc[t] = wcd[t];
  else if (t < 192) sbc[t - 128] = bcd[t - 128];
  const int w = t & 63;
  const int cg = t >> 6;
  const float* xb = x + (((size_t)b * 512) * 128 + h) * 128 + w0 + w;
  u16* ob = in1 + ((size_t)(b * 130 + h + 1) * 130 + (w0 + 1)) * 576;
#pragma unroll 1
  for (int cc = 0; cc < 4; ++cc) {
    const int c0 = cc * 128;
#pragma unroll
    for (int j = 0; j < 32; ++j) {
      int cl = j * 4 + cg;
      tile[cl * 65 + w] = f2bf(xb[(size_t)(c0 + cl) * 16384]);
    }
    __syncthreads();
#pragma unroll
    for (int k = 0; k < 4; ++k) {
      int idx = k * 256 + t;
      int ww = idx >> 4, c8 = (idx & 15) * 8;
      union { uint4 u; u16 s[8]; } o;
#pragma unroll
      for (int i = 0; i < 8; ++i) o.s[i] = tile[(c8 + i) * 65 + ww];
      *(uint4*)(ob + (size_t)ww * 576 + c0 + c8) = o.u;
    }
    __syncthreads();
  }
  // coord-conv features, channels 512..575
  const int px = t >> 2, cq = (t & 3) * 16;
  const float fw = (float)(w0 + px), fh = (float)h;
  u16* gp = ob + (size_t)px * 576 + 512 + cq;
#pragma unroll
  for (int j = 0; j < 2; ++j) {
    union { uint4 u; u16 s[8]; } o;
#pragma unroll
    for (int i = 0; i < 8; ++i) {
      int c = cq + j * 8 + i;
      float v = swc[2 * c] * fw + swc[2 * c + 1] * fh + sbc[c];
      o.s[i] = f2bf(fmaxf(v, 0.f));
    }
    *(uint4*)(gp + j * 8) = o.u;
  }
}

// ------- 3x3 conv implicit-GEMM MFMA, double-buffered slab staging ----------
// Per 32-ch slab (cb): [3 rows][130 px][32 ch] in LDS; slab cb+1 is staged
// (async global_load_lds) BEFORE computing cb's 9 taps, so the barrier drain
// at the top of cb+1 finds the loads already complete (~2000 cyc of overlap).
// Weights bypass LDS (coalesced L2 reads), software-pipelined one tap ahead.
// in : [4][130][130][CIN] bf16 (zero halo). wp: [CIN/32][9][COUT][32] bf16.
// grid = flat (COUT/BN)*512, XCD-swizzled. block = 256 (4 waves, 2x2).
template <int CIN, int COUT, int BN>
__global__ __launch_bounds__(256) void conv3x3_k(const u16* __restrict__ in,
                                                 const u16* __restrict__ wp,
                                                 const float* __restrict__ bias,
                                                 u16* __restrict__ out, int Hp,
                                                 int Wp, int opy, int opx,
                                                 float* __restrict__ stats,
                                                 int gsLog2, int nG) {
  constexpr int CB = CIN / 32;
  constexpr int WN = BN / 2;
  constexpr int NT = WN / 16;
  constexpr int ROWCH = 520;       // 16B chunks per staged row (130*32*2/16)
  constexpr int NCH = 3 * ROWCH;   // 1560 chunks = 24960 B per buffer
  constexpr int BUFE = 3 * 130 * 32;  // u16 elements per buffer
  static_assert(BN == 128 || BN == 64, "");
  __shared__ u16 As3[2 * BUFE];
  __shared__ float redS[8], redQ[8];

  const int t = threadIdx.x;
  const int L = gridDim.x;
  const int work = (blockIdx.x & 7) * (L >> 3) + (blockIdx.x >> 3);
  const int xt = work >> 9;
  const int rem = work & 511;
  const int b = rem >> 7, h = rem & 127;
  const int n0 = xt * BN;

  const int lane = t & 63, wv = t >> 6;
  const int wm = wv & 1, wn = wv >> 1;
  const int ln = lane & 15, lq = lane >> 4;

  if (t < 8) { redS[t] = 0.f; redQ[t] = 0.f; }

  f32x4 acc[4][NT];
  const f32x4 zero = {0.f, 0.f, 0.f, 0.f};
#pragma unroll
  for (int i = 0; i < 4; ++i)
#pragma unroll
    for (int j = 0; j < NT; ++j) acc[i][j] = zero;

  const u16* inb = in + ((size_t)b * 130 + h) * 130 * CIN;

  // per-thread staging geometry (constant across cb)
  int sc[7], srp[7], sqs[7];
#pragma unroll
  for (int it = 0; it < 7; ++it) {
    int c = it * 256 + t;
    sc[it] = (c < NCH) ? c : -1;
    int r = (c >= 2 * ROWCH) ? 2 : (c >= ROWCH ? 1 : 0);
    int wch = c - r * ROWCH;
    int pxi = wch >> 2, q = wch & 3;
    srp[it] = (r * 130 + pxi) * CIN + (q ^ ((pxi >> 1) & 3)) * 8;
    sqs[it] = c * 8;
  }

  auto stage = [&](int cb, int sel) {
    const u16* slab = inb + cb * 32;
    u16* dst = &As3[sel * BUFE];
#pragma unroll
    for (int it = 0; it < 7; ++it)
      if (sc[it] >= 0) GLD_LDS16(slab + srp[it], dst + sqs[it]);
  };

  stage(0, 0);

  const u16* wbase0 = wp + ((size_t)n0 + wn * WN + ln) * 32 + lq * 8;

#pragma unroll 1
  for (int cb = 0; cb < CB; ++cb) {
    __syncthreads();  // buf[cb&1] staged; prev readers of buf[1-cur] done
    const int cur = cb & 1;
    if (cb + 1 < CB) stage(cb + 1, 1 - cur);
    const u16* wcb = wbase0 + (size_t)(cb * 9) * COUT * 32;
    const u16* As = &As3[cur * BUFE];

    bf16x8 fb[NT], fbn[NT];
#pragma unroll
    for (int j = 0; j < NT; ++j)
      fb[j] = *(const bf16x8*)(wcb + j * 512);
#pragma unroll
    for (int dydx = 0; dydx < 9; ++dydx) {
      const int dy = dydx / 3, dx = dydx % 3;
      if (dydx < 8) {
#pragma unroll
        for (int j = 0; j < NT; ++j)
          fbn[j] = *(const bf16x8*)(wcb + (size_t)(dydx + 1) * COUT * 32 + j * 512);
      }
      bf16x8 fa[4];
#pragma unroll
      for (int i = 0; i < 4; ++i) {
        int pxl = dx + wm * 64 + i * 16 + ln;
        int qs = lq ^ ((pxl >> 1) & 3);
        fa[i] = *(const bf16x8*)&As[((dy * 130 + pxl) << 5) + qs * 8];
      }
#pragma unroll
      for (int i = 0; i < 4; ++i)
#pragma unroll
        for (int j = 0; j < NT; ++j)
          acc[i][j] = __builtin_amdgcn_mfma_f32_16x16x32_bf16(fa[i], fb[j],
                                                              acc[i][j], 0, 0, 0);
#pragma unroll
      for (int j = 0; j < NT; ++j) fb[j] = fbn[j];
    }
  }

  // epilogue: store bf16 + fused GN stats (sum / sumsq per group)
#pragma unroll
  for (int j = 0; j < NT; ++j) {
    const int n = n0 + wn * WN + j * 16 + ln;
    const float bv = bias[n];
    float sj = 0.f, qj = 0.f;
#pragma unroll
    for (int i = 0; i < 4; ++i) {
#pragma unroll
      for (int r = 0; r < 4; ++r) {
        const int w = wm * 64 + i * 16 + lq * 4 + r;
        u16 st = f2bf(acc[i][j][r] + bv);
        out[((size_t)(b * Hp + h + opy) * Wp + (w + opx)) * COUT + n] = st;
        float vq = bf2f(st);
        sj += vq;
        qj += vq * vq;
      }
    }
    sj += __shfl_xor(sj, 16, 64);
    sj += __shfl_xor(sj, 32, 64);
    qj += __shfl_xor(qj, 16, 64);
    qj += __shfl_xor(qj, 32, 64);
    if (lq == 0) {
      int gl = (wn * WN + j * 16 + ln) >> gsLog2;
      atomicAdd(&redS[gl], sj);
      atomicAdd(&redQ[gl], qj);
    }
  }
  __syncthreads();
  if (t < (BN >> gsLog2)) {
    int g = (n0 >> gsLog2) + t;
    atomicAdd(&stats[b * nG + g], redS[t]);
    atomicAdd(&stats[4 * nG + b * nG + g], redQ[t]);
  }
}

// -------- fused GN coef + normalize + ReLU in place (bf16) ------------------
__global__ __launch_bounds__(256) void gn_norm(u16* __restrict__ buf,
                                               const float* __restrict__ stats,
                                               const float* __restrict__ gamma,
                                               const float* __restrict__ beta,
                                               int C, int gsLog2, int nG,
                                               float invCnt, int Hp, int Wp,
                                               int py, int px) {
  const int t = threadIdx.x;
  const int mt = blockIdx.x;
  const int b = mt >> 7, h = mt & 127;
  __shared__ float la[256], lb[256];
  for (int i = t; i < C; i += 256) {
    int g = i >> gsLog2;
    float mean = stats[b * nG + g] * invCnt;
    float m2 = stats[4 * nG + b * nG + g] * invCnt;
    float rstd = rsqrtf(m2 - mean * mean + 1e-5f);
    float a = gamma[i] * rstd;
    la[i] = a;
    lb[i] = beta[i] - mean * a;
  }
  __syncthreads();
  u16* row = buf + ((size_t)(b * Hp + h + py) * Wp + px) * C;
  const int n8 = 128 * C / 8;
  for (int v = t; v < n8; v += 256) {
    uint4 d = *(uint4*)(row + v * 8);
    int c0 = (v * 8) & (C - 1);
    u16* pp = (u16*)&d;
    union { uint4 u; u16 s[8]; } o;
#pragma unroll
    for (int i = 0; i < 8; ++i) {
      float xx = bf2f(pp[i]);
      float y = la[c0 + i] * xx + lb[c0 + i];
      o.s[i] = f2bf(fmaxf(y, 0.f));
    }
    *(uint4*)(row + v * 8) = o.u;
  }
}

// -------- masked mean pooling (computes + applies GN3 + ReLU on the fly) ----
__global__ __launch_bounds__(256) void pool_k(const u16* __restrict__ h3,
                                              const int* __restrict__ masks,
                                              const float* __restrict__ stats,
                                              const float* __restrict__ gamma,
                                              const float* __restrict__ beta,
                                              float* __restrict__ gsum,
                                              float* __restrict__ gcnt) {
  const int t = threadIdx.x;
  const int b = blockIdx.x >> 6, chunk = blockIdx.x & 63;
  __shared__ float ls[33 * 64];
  __shared__ float lc[33];
  for (int i = t; i < 33 * 64; i += 256) ls[i] = 0.f;
  if (t < 33) lc[t] = 0.f;
  const int c = t & 63;
  const int g = c >> 4;
  const float invCnt = 1.f / (16384.f * 16.f);
  float mean = stats[b * 4 + g] * invCnt;
  float m2 = stats[16 + b * 4 + g] * invCnt;
  float rstd = rsqrtf(m2 - mean * mean + 1e-5f);
  const float a = gamma[c] * rstd;
  const float cc = beta[c] - mean * a;
  __syncthreads();
  const int p0 = chunk * 256;
  for (int i = 0; i < 64; ++i) {
    int p = p0 + i * 4 + (t >> 6);
    int id = masks[b * 16384 + p];
    float v = bf2f(h3[((size_t)b * 16384 + p) * 64 + c]);
    v = fmaxf(a * v + cc, 0.f);
    atomicAdd(&ls[id * 64 + c], v);
    if (c == 0) atomicAdd(&lc[id], 1.f);
  }
  __syncthreads();
  for (int i = t; i < 33 * 64; i += 256) atomicAdd(&gsum[b * 2112 + i], ls[i]);
  if (t < 33) atomicAdd(&gcnt[b * 33 + t], lc[t]);
}

// ---------------- heads: boxes [4][32][7] then scores [4][32] ---------------
__global__ __launch_bounds__(256) void heads_k(const float* __restrict__ gsum,
                                               const float* __restrict__ gcnt,
                                               const float* __restrict__ wbox,
                                               const float* __restrict__ bbox,
                                               const float* __restrict__ wconf,
                                               const float* __restrict__ bconf,
                                               float* __restrict__ out) {
  int idx = blockIdx.x * 256 + threadIdx.x;
  if (idx >= 1024) return;
  if (idx < 896) {
    int b = idx / 224, r = idx % 224;
    int o = r / 7, k = r % 7;
    float inv = 1.f / fmaxf(gcnt[b * 33 + o + 1], 1e-4f);
    const float* ps = gsum + (b * 33 + o + 1) * 64;
    float s = 0.f;
    for (int c = 0; c < 64; ++c) s += ps[c] * wbox[k * 64 + c];
    out[idx] = s * inv + bbox[k];
  } else {
    int i = idx - 896;
    int b = i >> 5, o = i & 31;
    float inv = 1.f / fmaxf(gcnt[b * 33 + o + 1], 1e-4f);
    const float* ps = gsum + (b * 33 + o + 1) * 64;
    float s = 0.f;
    for (int c = 0; c < 64; ++c) s += ps[c] * wconf[c];
    out[896 + i] = s * inv + bconf[0];
  }
}

extern "C" void kernel_launch(void* const* d_in, const int* in_sizes, int n_in,
                              void* d_out, int out_size, void* d_ws,
                              size_t ws_size, hipStream_t stream) {
  (void)in_sizes; (void)n_in; (void)out_size; (void)ws_size;
  const float* x       = (const float*)d_in[0];
  const int*   masks   = (const int*)d_in[1];
  const float* w_coord = (const float*)d_in[2];
  const float* b_coord = (const float*)d_in[3];
  const float* w1  = (const float*)d_in[4];
  const float* b1  = (const float*)d_in[5];
  const float* g1  = (const float*)d_in[6];
  const float* bt1 = (const float*)d_in[7];
  const float* w2  = (const float*)d_in[8];
  const float* b2  = (const float*)d_in[9];
  const float* g2  = (const float*)d_in[10];
  const float* bt2 = (const float*)d_in[11];
  const float* w3  = (const float*)d_in[12];
  const float* b3  = (const float*)d_in[13];
  const float* g3  = (const float*)d_in[14];
  const float* bt3 = (const float*)d_in[15];
  const float* wbox  = (const float*)d_in[16];
  const float* bbox  = (const float*)d_in[17];
  const float* wconf = (const float*)d_in[18];
  const float* bconf = (const float*)d_in[19];
  float* out = (float*)d_out;

  char* ws = (char*)d_ws;
  size_t off = 0;
  auto take = [&](size_t bytes) {
    size_t o = off;
    off += (bytes + 255) & ~(size_t)255;
    return o;
  };
  u16* in1 = (u16*)(ws + take((size_t)4 * 130 * 130 * 576 * 2));
  u16* in2 = (u16*)(ws + take((size_t)4 * 130 * 130 * 256 * 2));
  u16* in3 = (u16*)(ws + take((size_t)4 * 130 * 130 * 128 * 2));
  u16* wp1 = (u16*)(ws + take((size_t)9 * 576 * 256 * 2));
  u16* wp2 = (u16*)(ws + take((size_t)9 * 256 * 128 * 2));
  u16* wp3 = (u16*)(ws + take((size_t)9 * 128 * 64 * 2));
  float* smallb = (float*)(ws + take(8708 * 4));
  u16* h3 = in1;  // alias: in1 dead after conv1, h3 written by conv3

  float* s1   = smallb;         // 64
  float* s2   = smallb + 64;    // 32
  float* s3   = smallb + 96;    // 32
  float* psum = smallb + 128;   // 8448
  float* pcnt = smallb + 8576;  // 132

  // 1. zero accumulators + halos (one launch)
  init_k<<<dim3(83), 256, 0, stream>>>(smallb, in1, in2, in3);

  // 2. weight repack (one launch)
  repack_all<<<dim3(6624), 256, 0, stream>>>(w1, wp1, w2, wp2, w3, wp3);

  // 3. conv1 input: x transpose + coord features (fused)
  transpose_x<<<dim3(1024), 256, 0, stream>>>(x, w_coord, b_coord, in1);

  // 4. conv1 (+fused GN1 stats) + GN1 normalize
  conv3x3_k<576, 256, 128><<<dim3(1024), 256, 0, stream>>>(in1, wp1, b1, in2, 130, 130, 1, 1, s1, 5, 8);
  gn_norm<<<dim3(512), 256, 0, stream>>>(in2, s1, g1, bt1, 256, 5, 8, 1.f / (16384.f * 32.f), 130, 130, 1, 1);

  // 5. conv2 (+fused GN2 stats) + GN2 normalize
  conv3x3_k<256, 128, 128><<<dim3(512), 256, 0, stream>>>(in2, wp2, b2, in3, 130, 130, 1, 1, s2, 5, 4);
  gn_norm<<<dim3(512), 256, 0, stream>>>(in3, s2, g2, bt2, 128, 5, 4, 1.f / (16384.f * 32.f), 130, 130, 1, 1);

  // 6. conv3 (+fused GN3 stats; GN3+ReLU applied inside pooling)
  conv3x3_k<128, 64, 64><<<dim3(512), 256, 0, stream>>>(in3, wp3, b3, h3, 128, 128, 0, 0, s3, 4, 4);

  // 7. pooling (computes GN3 affine itself) + heads
  pool_k<<<dim3(256), 256, 0, stream>>>(h3, masks, s3, g3, bt3, psum, pcnt);
  heads_k<<<dim3(4), 256, 0, stream>>>(psum, pcnt, wbox, bbox, wconf, bconf, out);
}

// Round 7
// 561.875 us; speedup vs baseline: 1.0616x; 1.0616x over previous
//
#include <hip/hip_runtime.h>

typedef unsigned short u16;
typedef unsigned int u32;
typedef __bf16 bf16x8 __attribute__((ext_vector_type(8)));
typedef float f32x4 __attribute__((ext_vector_type(4)));

__device__ __forceinline__ u16 f2bf(float f) {
  u32 u = __float_as_uint(f);
  u += 0x7fffu + ((u >> 16) & 1u);
  return (u16)(u >> 16);
}
__device__ __forceinline__ float bf2f(u16 h) {
  return __uint_as_float(((u32)h) << 16);
}

#define GLD_LDS16(g, l)                                                        \
  __builtin_amdgcn_global_load_lds(                                            \
      (__attribute__((address_space(1))) void*)(g),                            \
      (__attribute__((address_space(3))) void*)(l), 16, 0, 0)

// ---------------- prep: init + weight repack + input transpose, one launch --
// blocks [0,83): zero smallb + halos of in1/in2/in3
// blocks [83,6707): repack w1/w2/w3 OIHW fp32 -> [CIN/32][9][COUT][32] bf16
// blocks [6707,7731): x NCHW fp32 -> in1 NHWC bf16 + coord features
__global__ __launch_bounds__(256) void prep_k(
    float* smallb, u16* in1, u16* in2, u16* in3, const float* __restrict__ w1,
    u16* __restrict__ wp1, const float* __restrict__ w2, u16* __restrict__ wp2,
    const float* __restrict__ w3, u16* __restrict__ wp3,
    const float* __restrict__ x, const float* __restrict__ wcd,
    const float* __restrict__ bcd) {
  const int bid = blockIdx.x;
  const int t = threadIdx.x;
  __shared__ u16 tile[128 * 65];
  __shared__ float swc[128], sbc[64];

  if (bid < 83) {
    if (bid < 35) {
      int i = bid * 256 + t;
      if (i < 8708) smallb[i] = 0.f;
      return;
    }
    u16* buf;
    int C, sub;
    if (bid < 51)      { buf = in1; C = 576; sub = bid - 35; }
    else if (bid < 67) { buf = in2; C = 256; sub = bid - 51; }
    else               { buf = in3; C = 128; sub = bid - 67; }
    int b = sub >> 2, s = sub & 3;
    int npx = (s < 2) ? 130 : 128;
    u32* base = (u32*)(buf + (size_t)b * 130 * 130 * C);
    int C2 = C >> 1;
    int total = npx * C2;
    for (int i = t; i < total; i += 256) {
      int p = i / C2, r = i - p * C2;
      int y, xx;
      if (s == 0)      { y = 0;     xx = p; }
      else if (s == 1) { y = 129;   xx = p; }
      else if (s == 2) { y = p + 1; xx = 0; }
      else             { y = p + 1; xx = 129; }
      base[(y * 130 + xx) * C2 + r] = 0u;
    }
    return;
  }
  if (bid < 6707) {
    int rel = bid - 83;
    const float* src;
    u16* dst;
    int CIN, COUT, total, base;
    if (rel < 5184)      { src = w1; dst = wp1; CIN = 576; COUT = 256; total = 1327104; base = rel; }
    else if (rel < 6336) { src = w2; dst = wp2; CIN = 256; COUT = 128; total = 294912;  base = rel - 5184; }
    else                 { src = w3; dst = wp3; CIN = 128; COUT = 64;  total = 73728;   base = rel - 6336; }
    int idx = base * 256 + t;
    if (idx >= total) return;
    int kc = idx & 31;
    int n = (idx >> 5) % COUT;
    int q = idx / (32 * COUT);
    int dydx = q % 9, cb = q / 9;
    dst[idx] = f2bf(src[((size_t)n * CIN + cb * 32 + kc) * 9 + dydx]);
    return;
  }
  // transpose branch
  const int tb = bid - 6707;
  const int b = tb >> 8, h = (tb >> 1) & 127, half = tb & 1;
  const int w0 = half * 64;
  if (t < 128) swc[t] = wcd[t];
  else if (t < 192) sbc[t - 128] = bcd[t - 128];
  const int w = t & 63;
  const int cg = t >> 6;
  const float* xb = x + (((size_t)b * 512) * 128 + h) * 128 + w0 + w;
  u16* ob = in1 + ((size_t)(b * 130 + h + 1) * 130 + (w0 + 1)) * 576;
#pragma unroll 1
  for (int cc = 0; cc < 4; ++cc) {
    const int c0 = cc * 128;
#pragma unroll
    for (int j = 0; j < 32; ++j) {
      int cl = j * 4 + cg;
      tile[cl * 65 + w] = f2bf(xb[(size_t)(c0 + cl) * 16384]);
    }
    __syncthreads();
#pragma unroll
    for (int k = 0; k < 4; ++k) {
      int idx = k * 256 + t;
      int ww = idx >> 4, c8 = (idx & 15) * 8;
      union { uint4 u; u16 s[8]; } o;
#pragma unroll
      for (int i = 0; i < 8; ++i) o.s[i] = tile[(c8 + i) * 65 + ww];
      *(uint4*)(ob + (size_t)ww * 576 + c0 + c8) = o.u;
    }
    __syncthreads();
  }
  const int px = t >> 2, cq = (t & 3) * 16;
  const float fw = (float)(w0 + px), fh = (float)h;
  u16* gp = ob + (size_t)px * 576 + 512 + cq;
#pragma unroll
  for (int j = 0; j < 2; ++j) {
    union { uint4 u; u16 s[8]; } o;
#pragma unroll
    for (int i = 0; i < 8; ++i) {
      int c = cq + j * 8 + i;
      float v = swc[2 * c] * fw + swc[2 * c + 1] * fh + sbc[c];
      o.s[i] = f2bf(fmaxf(v, 0.f));
    }
    *(uint4*)(gp + j * 8) = o.u;
  }
}

// ------- 3x3 conv implicit-GEMM MFMA, dbuf slab + optional fused input GN ---
// Per 32-ch slab (cb): LDS [3 rows][130 px][32 ch]; NORM applies the previous
// layer's GroupNorm affine + ReLU in-LDS after the staging barrier (halo->0),
// so convs consume RAW upstream output and gn_norm passes disappear.
// Weights bypass LDS (L2-resident), pipelined one tap ahead; fa prefetched
// one tap ahead; tap-0 fb issued before next-slab staging (vmcnt ordering).
template <int CIN, int COUT, int BN, bool NORM>
__global__ __launch_bounds__(256) void conv3x3_k(
    const u16* __restrict__ in, const u16* __restrict__ wp,
    const float* __restrict__ bias, u16* __restrict__ out, int Hp, int Wp,
    int opy, int opx, float* __restrict__ stats, int gsLog2, int nG,
    const float* __restrict__ inStats, const float* __restrict__ inGamma,
    const float* __restrict__ inBeta, int inGsLog2, int inNG) {
  constexpr int CB = CIN / 32;
  constexpr int WN = BN / 2;
  constexpr int NT = WN / 16;
  constexpr int ROWCH = 520;          // 16B chunks per staged row
  constexpr int NCH = 3 * ROWCH;      // 1560 chunks per buffer
  constexpr int BUFE = 3 * 130 * 32;  // u16 per buffer
  static_assert(BN == 128 || BN == 64, "");
  __shared__ u16 As3[2 * BUFE];
  __shared__ float redS[8], redQ[8];
  __shared__ float la[NORM ? CIN : 1], lb[NORM ? CIN : 1];

  const int t = threadIdx.x;
  const int L = gridDim.x;
  const int work = (blockIdx.x & 7) * (L >> 3) + (blockIdx.x >> 3);
  const int xt = work >> 9;
  const int rem = work & 511;
  const int b = rem >> 7, h = rem & 127;
  const int n0 = xt * BN;

  const int lane = t & 63, wv = t >> 6;
  const int wm = wv & 1, wn = wv >> 1;
  const int ln = lane & 15, lq = lane >> 4;

  if (t < 8) { redS[t] = 0.f; redQ[t] = 0.f; }
  if (NORM) {
    const float invCnt = 1.f / (16384.f * 32.f);  // both GN1 and GN2: gs 32
    for (int i = t; i < CIN; i += 256) {
      int g = i >> inGsLog2;
      float mean = inStats[b * inNG + g] * invCnt;
      float m2 = inStats[4 * inNG + b * inNG + g] * invCnt;
      float rstd = rsqrtf(m2 - mean * mean + 1e-5f);
      float a = inGamma[i] * rstd;
      la[i] = a;
      lb[i] = inBeta[i] - mean * a;
    }
  }

  f32x4 acc[4][NT];
  const f32x4 zero = {0.f, 0.f, 0.f, 0.f};
#pragma unroll
  for (int i = 0; i < 4; ++i)
#pragma unroll
    for (int j = 0; j < NT; ++j) acc[i][j] = zero;

  const u16* inb = in + ((size_t)b * 130 + h) * 130 * CIN;

  // per-thread staging geometry (constant across cb)
  int sc[7], srp[7], sqs[7], hz[7];
#pragma unroll
  for (int it = 0; it < 7; ++it) {
    int c = it * 256 + t;
    sc[it] = (c < NCH) ? c : -1;
    int r = (c >= 2 * ROWCH) ? 2 : (c >= ROWCH ? 1 : 0);
    int wch = c - r * ROWCH;
    int pxi = wch >> 2, q = wch & 3;
    srp[it] = (r * 130 + pxi) * CIN + (q ^ ((pxi >> 1) & 3)) * 8;
    sqs[it] = c * 8;
    hz[it] = (pxi == 0) || (pxi == 129) || (r == 0 && h == 0) ||
             (r == 2 && h == 127);
  }

  auto stage = [&](int cb, int sel) {
    const u16* slab = inb + cb * 32;
    u16* dst = &As3[sel * BUFE];
#pragma unroll
    for (int it = 0; it < 7; ++it)
      if (sc[it] >= 0) GLD_LDS16(slab + srp[it], dst + sqs[it]);
  };

  stage(0, 0);

  const u16* wbase0 = wp + ((size_t)n0 + wn * WN + ln) * 32 + lq * 8;

#pragma unroll 1
  for (int cb = 0; cb < CB; ++cb) {
    __syncthreads();  // buf[cur] staged; prior readers of buf[other] done
    const int cur = cb & 1;
    const u16* wcb = wbase0 + (size_t)(cb * 9) * COUT * 32;
    u16* Asw = &As3[cur * BUFE];

    // issue tap-0 weights FIRST (before staging) so their wait doesn't
    // require draining the HBM staging queue (vmcnt is issue-ordered).
    bf16x8 fb[NT], fbn[NT];
#pragma unroll
    for (int j = 0; j < NT; ++j) fb[j] = *(const bf16x8*)(wcb + j * 512);

    if (NORM) {
      // in-LDS: y = max(a*x+b, 0); halo pixels stay exactly 0
#pragma unroll
      for (int it = 0; it < 7; ++it) {
        if (sc[it] < 0) continue;
        uint4* p = (uint4*)&Asw[sqs[it]];
        if (hz[it]) {
          *p = (uint4){0u, 0u, 0u, 0u};
        } else {
          int chb = cb * 32 + (srp[it] & 31);
          union { uint4 u; u16 s[8]; } d;
          d.u = *p;
#pragma unroll
          for (int e = 0; e < 8; ++e) {
            float v = la[chb + e] * bf2f(d.s[e]) + lb[chb + e];
            d.s[e] = f2bf(fmaxf(v, 0.f));
          }
          *p = d.u;
        }
      }
      __syncthreads();  // LDS-only barrier (no vmem outstanding to drain)
    }

    if (cb + 1 < CB) stage(cb + 1, 1 - cur);

    // fa prefetch one tap ahead
    bf16x8 fa[4], fan[4];
#pragma unroll
    for (int i = 0; i < 4; ++i) {
      int pxl = wm * 64 + i * 16 + ln;  // tap 0: dy=0,dx=0
      int qs = lq ^ ((pxl >> 1) & 3);
      fa[i] = *(const bf16x8*)&Asw[(pxl << 5) + qs * 8];
    }
#pragma unroll
    for (int dydx = 0; dydx < 9; ++dydx) {
      if (dydx < 8) {
        const int dyn = (dydx + 1) / 3, dxn = (dydx + 1) % 3;
#pragma unroll
        for (int j = 0; j < NT; ++j)
          fbn[j] = *(const bf16x8*)(wcb + (size_t)(dydx + 1) * COUT * 32 + j * 512);
#pragma unroll
        for (int i = 0; i < 4; ++i) {
          int pxl = dxn + wm * 64 + i * 16 + ln;
          int qs = lq ^ ((pxl >> 1) & 3);
          fan[i] = *(const bf16x8*)&Asw[((dyn * 130 + pxl) << 5) + qs * 8];
        }
      }
#pragma unroll
      for (int i = 0; i < 4; ++i)
#pragma unroll
        for (int j = 0; j < NT; ++j)
          acc[i][j] = __builtin_amdgcn_mfma_f32_16x16x32_bf16(fa[i], fb[j],
                                                              acc[i][j], 0, 0, 0);
#pragma unroll
      for (int j = 0; j < NT; ++j) fb[j] = fbn[j];
#pragma unroll
      for (int i = 0; i < 4; ++i) fa[i] = fan[i];
    }
  }

  // epilogue: store bf16 + fused GN stats (sum / sumsq per group)
#pragma unroll
  for (int j = 0; j < NT; ++j) {
    const int n = n0 + wn * WN + j * 16 + ln;
    const float bv = bias[n];
    float sj = 0.f, qj = 0.f;
#pragma unroll
    for (int i = 0; i < 4; ++i) {
#pragma unroll
      for (int r = 0; r < 4; ++r) {
        const int w = wm * 64 + i * 16 + lq * 4 + r;
        u16 st = f2bf(acc[i][j][r] + bv);
        out[((size_t)(b * Hp + h + opy) * Wp + (w + opx)) * COUT + n] = st;
        float vq = bf2f(st);
        sj += vq;
        qj += vq * vq;
      }
    }
    sj += __shfl_xor(sj, 16, 64);
    sj += __shfl_xor(sj, 32, 64);
    qj += __shfl_xor(qj, 16, 64);
    qj += __shfl_xor(qj, 32, 64);
    if (lq == 0) {
      int gl = (wn * WN + j * 16 + ln) >> gsLog2;
      atomicAdd(&redS[gl], sj);
      atomicAdd(&redQ[gl], qj);
    }
  }
  __syncthreads();
  if (t < (BN >> gsLog2)) {
    int g = (n0 >> gsLog2) + t;
    atomicAdd(&stats[b * nG + g], redS[t]);
    atomicAdd(&stats[4 * nG + b * nG + g], redQ[t]);
  }
}

// -------- masked mean pooling (computes + applies GN3 + ReLU on the fly) ----
__global__ __launch_bounds__(256) void pool_k(const u16* __restrict__ h3,
                                              const int* __restrict__ masks,
                                              const float* __restrict__ stats,
                                              const float* __restrict__ gamma,
                                              const float* __restrict__ beta,
                                              float* __restrict__ gsum,
                                              float* __restrict__ gcnt) {
  const int t = threadIdx.x;
  const int b = blockIdx.x >> 6, chunk = blockIdx.x & 63;
  __shared__ float ls[33 * 64];
  __shared__ float lc[33];
  for (int i = t; i < 33 * 64; i += 256) ls[i] = 0.f;
  if (t < 33) lc[t] = 0.f;
  const int c = t & 63;
  const int g = c >> 4;
  const float invCnt = 1.f / (16384.f * 16.f);
  float mean = stats[b * 4 + g] * invCnt;
  float m2 = stats[16 + b * 4 + g] * invCnt;
  float rstd = rsqrtf(m2 - mean * mean + 1e-5f);
  const float a = gamma[c] * rstd;
  const float cc = beta[c] - mean * a;
  __syncthreads();
  const int p0 = chunk * 256;
  for (int i = 0; i < 64; ++i) {
    int p = p0 + i * 4 + (t >> 6);
    int id = masks[b * 16384 + p];
    float v = bf2f(h3[((size_t)b * 16384 + p) * 64 + c]);
    v = fmaxf(a * v + cc, 0.f);
    atomicAdd(&ls[id * 64 + c], v);
    if (c == 0) atomicAdd(&lc[id], 1.f);
  }
  __syncthreads();
  for (int i = t; i < 33 * 64; i += 256) atomicAdd(&gsum[b * 2112 + i], ls[i]);
  if (t < 33) atomicAdd(&gcnt[b * 33 + t], lc[t]);
}

// ---------------- heads: boxes [4][32][7] then scores [4][32] ---------------
__global__ __launch_bounds__(256) void heads_k(const float* __restrict__ gsum,
                                               const float* __restrict__ gcnt,
                                               const float* __restrict__ wbox,
                                               const float* __restrict__ bbox,
                                               const float* __restrict__ wconf,
                                               const float* __restrict__ bconf,
                                               float* __restrict__ out) {
  int idx = blockIdx.x * 256 + threadIdx.x;
  if (idx >= 1024) return;
  if (idx < 896) {
    int b = idx / 224, r = idx % 224;
    int o = r / 7, k = r % 7;
    float inv = 1.f / fmaxf(gcnt[b * 33 + o + 1], 1e-4f);
    const float* ps = gsum + (b * 33 + o + 1) * 64;
    float s = 0.f;
    for (int c = 0; c < 64; ++c) s += ps[c] * wbox[k * 64 + c];
    out[idx] = s * inv + bbox[k];
  } else {
    int i = idx - 896;
    int b = i >> 5, o = i & 31;
    float inv = 1.f / fmaxf(gcnt[b * 33 + o + 1], 1e-4f);
    const float* ps = gsum + (b * 33 + o + 1) * 64;
    float s = 0.f;
    for (int c = 0; c < 64; ++c) s += ps[c] * wconf[c];
    out[896 + i] = s * inv + bconf[0];
  }
}

extern "C" void kernel_launch(void* const* d_in, const int* in_sizes, int n_in,
                              void* d_out, int out_size, void* d_ws,
                              size_t ws_size, hipStream_t stream) {
  (void)in_sizes; (void)n_in; (void)out_size; (void)ws_size;
  const float* x       = (const float*)d_in[0];
  const int*   masks   = (const int*)d_in[1];
  const float* w_coord = (const float*)d_in[2];
  const float* b_coord = (const float*)d_in[3];
  const float* w1  = (const float*)d_in[4];
  const float* b1  = (const float*)d_in[5];
  const float* g1  = (const float*)d_in[6];
  const float* bt1 = (const float*)d_in[7];
  const float* w2  = (const float*)d_in[8];
  const float* b2  = (const float*)d_in[9];
  const float* g2  = (const float*)d_in[10];
  const float* bt2 = (const float*)d_in[11];
  const float* w3  = (const float*)d_in[12];
  const float* b3  = (const float*)d_in[13];
  const float* g3  = (const float*)d_in[14];
  const float* bt3 = (const float*)d_in[15];
  const float* wbox  = (const float*)d_in[16];
  const float* bbox  = (const float*)d_in[17];
  const float* wconf = (const float*)d_in[18];
  const float* bconf = (const float*)d_in[19];
  float* out = (float*)d_out;

  char* ws = (char*)d_ws;
  size_t off = 0;
  auto take = [&](size_t bytes) {
    size_t o = off;
    off += (bytes + 255) & ~(size_t)255;
    return o;
  };
  u16* in1 = (u16*)(ws + take((size_t)4 * 130 * 130 * 576 * 2));
  u16* in2 = (u16*)(ws + take((size_t)4 * 130 * 130 * 256 * 2));
  u16* in3 = (u16*)(ws + take((size_t)4 * 130 * 130 * 128 * 2));
  u16* wp1 = (u16*)(ws + take((size_t)9 * 576 * 256 * 2));
  u16* wp2 = (u16*)(ws + take((size_t)9 * 256 * 128 * 2));
  u16* wp3 = (u16*)(ws + take((size_t)9 * 128 * 64 * 2));
  float* smallb = (float*)(ws + take(8708 * 4));
  u16* h3 = in1;  // alias: in1 dead after conv1, h3 written by conv3

  float* s1   = smallb;         // 64
  float* s2   = smallb + 64;    // 32
  float* s3   = smallb + 96;    // 32
  float* psum = smallb + 128;   // 8448
  float* pcnt = smallb + 8576;  // 132

  // 1. prep: init + repack + transpose (one launch)
  prep_k<<<dim3(7731), 256, 0, stream>>>(smallb, in1, in2, in3, w1, wp1, w2,
                                         wp2, w3, wp3, x, w_coord, b_coord);

  // 2. conv1 (raw out + GN1 stats)
  conv3x3_k<576, 256, 128, false><<<dim3(1024), 256, 0, stream>>>(
      in1, wp1, b1, in2, 130, 130, 1, 1, s1, 5, 8, nullptr, nullptr, nullptr, 0, 0);

  // 3. conv2 (applies GN1+ReLU in-LDS; raw out + GN2 stats)
  conv3x3_k<256, 128, 128, true><<<dim3(512), 256, 0, stream>>>(
      in2, wp2, b2, in3, 130, 130, 1, 1, s2, 5, 4, s1, g1, bt1, 5, 8);

  // 4. conv3 (applies GN2+ReLU in-LDS; raw out + GN3 stats)
  conv3x3_k<128, 64, 64, true><<<dim3(512), 256, 0, stream>>>(
      in3, wp3, b3, h3, 128, 128, 0, 0, s3, 4, 4, s2, g2, bt2, 5, 4);

  // 5. pooling (computes + applies GN3 affine itself) + heads
  pool_k<<<dim3(256), 256, 0, stream>>>(h3, masks, s3, g3, bt3, psum, pcnt);
  heads_k<<<dim3(4), 256, 0, stream>>>(psum, pcnt, wbox, bbox, wconf, bconf, out);
}